// Round 2
// 18234.459 us; speedup vs baseline: 1.2761x; 1.2761x over previous
//
#include <hip/hip_runtime.h>

#define T_STEPS 512
#define BATCH   64
#define CIN     512
#define CH      1024

typedef __attribute__((ext_vector_type(8))) short bf16x8;
typedef __attribute__((ext_vector_type(4))) float f32x4;

__device__ __forceinline__ unsigned short f2bf(float f) {
  unsigned int x = __float_as_uint(f);
  x += 0x7fffu + ((x >> 16) & 1u);   // RNE
  return (unsigned short)(x >> 16);
}
__device__ __forceinline__ float bf2f(unsigned short u) {
  return __uint_as_float(((unsigned int)u) << 16);
}

// ---------------------------------------------------------------------------
// fp32 [R][C] -> bf16 hi/lo [C][R] transpose+split (w = hi + lo to ~2^-18 rel)
// ---------------------------------------------------------------------------
__global__ __launch_bounds__(256) void transpose_cvt_split(
    const float* __restrict__ in, unsigned short* __restrict__ oh,
    unsigned short* __restrict__ ol, int R, int Cc)
{
  __shared__ float tile[32][33];
  const int tx = threadIdx.x & 31, ty = threadIdx.x >> 5;
  const int bx = blockIdx.x * 32;  // C offset
  const int by = blockIdx.y * 32;  // R offset
#pragma unroll
  for (int i = 0; i < 32; i += 8)
    tile[ty + i][tx] = in[(size_t)(by + ty + i) * Cc + bx + tx];
  __syncthreads();
#pragma unroll
  for (int i = 0; i < 32; i += 8) {
    float w = tile[tx][ty + i];
    unsigned short hi = f2bf(w);
    unsigned short lo = f2bf(w - bf2f(hi));
    size_t o = (size_t)(bx + ty + i) * R + by + tx;
    oh[o] = hi;
    ol[o] = lo;
  }
}

// ---------------------------------------------------------------------------
// fp32 -> bf16 elementwise (h0 = state).
// ---------------------------------------------------------------------------
__global__ void cvt_f32_bf16(const float* __restrict__ in,
                             unsigned short* __restrict__ outp, int n)
{
  int i = (blockIdx.x * blockDim.x + threadIdx.x) * 4;
  if (i < n) {
    float4 v = *(const float4*)(in + i);
    ushort4 o;
    o.x = f2bf(v.x); o.y = f2bf(v.y); o.z = f2bf(v.z); o.w = f2bf(v.w);
    *(ushort4*)(outp + i) = o;
  }
}

// ---------------------------------------------------------------------------
// xp = inputs @ Wx + b, COMPENSATED bf16 GEMM -> fp32 output.
// A fp32 [32768][512] split to hi/lo in LDS; B = WxT hi/lo [1024][512].
// acc += ah*bh + ah*bl + al*bh  (error ~2^-18 rel, fp32 accumulate).
// 128x128 tile, BK=32, 256 threads (4 waves 2x2), 16x16x32 MFMA.
// ---------------------------------------------------------------------------
#define BM 128
#define BN 128
#define BK 32

__global__ __launch_bounds__(256) void gemm_xp(
    const float* __restrict__ A,
    const unsigned short* __restrict__ BTh,
    const unsigned short* __restrict__ BTl,
    const float* __restrict__ bias,
    float* __restrict__ C)                  // [32768][1024] f32 (out[1] region)
{
  __shared__ unsigned short Ah[BM][BK + 8];
  __shared__ unsigned short Al[BM][BK + 8];
  __shared__ unsigned short Bh[BN][BK + 8];
  __shared__ unsigned short Bl[BN][BK + 8];
  const int tid = threadIdx.x;
  const int w = tid >> 6, l = tid & 63;
  const int wm = (w >> 1) * 64, wn = (w & 1) * 64;
  const int q = l >> 4, m = l & 15;
  const int row0 = blockIdx.y * BM;
  const int col0 = blockIdx.x * BN;
  f32x4 acc[4][4];
#pragma unroll
  for (int i = 0; i < 4; i++)
#pragma unroll
    for (int j = 0; j < 4; j++) acc[i][j] = (f32x4){0.f, 0.f, 0.f, 0.f};

  for (int kt = 0; kt < CIN; kt += BK) {
    // A: 128 rows x 32 f32 = 1024 float4-chunks; 4 per thread -> hi/lo bf16
#pragma unroll
    for (int i = 0; i < 4; i++) {
      int cid = tid + i * 256;
      int r = cid >> 3, c4 = cid & 7;
      float4 v = *(const float4*)(A + (size_t)(row0 + r) * CIN + kt + c4 * 4);
      ushort4 hi, lo;
      hi.x = f2bf(v.x); lo.x = f2bf(v.x - bf2f(hi.x));
      hi.y = f2bf(v.y); lo.y = f2bf(v.y - bf2f(hi.y));
      hi.z = f2bf(v.z); lo.z = f2bf(v.z - bf2f(hi.z));
      hi.w = f2bf(v.w); lo.w = f2bf(v.w - bf2f(hi.w));
      *(ushort4*)(&Ah[r][c4 * 4]) = hi;
      *(ushort4*)(&Al[r][c4 * 4]) = lo;
    }
    // B: hi and lo arrays, each 128 rows x 32 bf16 = 512 16B-chunks
#pragma unroll
    for (int i = 0; i < 4; i++) {
      int cid = tid + i * 256;
      const unsigned short* src = (cid < 512) ? BTh : BTl;
      unsigned short (*dst)[BK + 8] = (cid < 512) ? Bh : Bl;
      int rem = cid & 511;
      int r = rem >> 2, c8 = rem & 3;
      uint4 u = *(const uint4*)(src + (size_t)(col0 + r) * CIN + kt + c8 * 8);
      *(uint4*)(&dst[r][c8 * 8]) = u;
    }
    __syncthreads();
    bf16x8 ah[4], al[4], bh[4], bl[4];
#pragma unroll
    for (int i = 0; i < 4; i++) {
      ah[i] = *(const bf16x8*)(&Ah[wm + i * 16 + m][q * 8]);
      al[i] = *(const bf16x8*)(&Al[wm + i * 16 + m][q * 8]);
    }
#pragma unroll
    for (int j = 0; j < 4; j++) {
      bh[j] = *(const bf16x8*)(&Bh[wn + j * 16 + m][q * 8]);
      bl[j] = *(const bf16x8*)(&Bl[wn + j * 16 + m][q * 8]);
    }
#pragma unroll
    for (int i = 0; i < 4; i++)
#pragma unroll
      for (int j = 0; j < 4; j++) {
        acc[i][j] = __builtin_amdgcn_mfma_f32_16x16x32_bf16(ah[i], bh[j], acc[i][j], 0, 0, 0);
        acc[i][j] = __builtin_amdgcn_mfma_f32_16x16x32_bf16(ah[i], bl[j], acc[i][j], 0, 0, 0);
        acc[i][j] = __builtin_amdgcn_mfma_f32_16x16x32_bf16(al[i], bh[j], acc[i][j], 0, 0, 0);
      }
    __syncthreads();
  }
  // epilogue: D layout col=lane&15, row=(lane>>4)*4+reg; fp32 store
#pragma unroll
  for (int i = 0; i < 4; i++) {
#pragma unroll
    for (int j = 0; j < 4; j++) {
      int col = col0 + wn + j * 16 + m;
      float bv = bias[col];
#pragma unroll
      for (int r = 0; r < 4; r++) {
        int row = row0 + wm + i * 16 + q * 4 + r;
        C[(size_t)row * CH + col] = acc[i][j][r] + bv;
      }
    }
  }
}

// ---------------------------------------------------------------------------
// Persistent scan: h_{t+1} = tanh(xp_t + h_t @ Wh), 512 steps.
// 16 WGs x 1024 threads; WG owns 64 cols; Wh as hi+lo bf16 (2 MFMAs/k-step).
//
// Cross-XCD h exchange WITHOUT __threadfence (no buffer_wbl2/buffer_inv L2
// walks on the per-step critical path):
//   - h writes:  16-bit relaxed AGENT atomic stores  (bypass -> coherence pt)
//   - h reads:   8-byte  relaxed AGENT atomic loads  (bypass stale L1/L2)
//   - barrier:   s_waitcnt vmcnt(0) drains ONLY the h-stores, then
//                relaxed agent fetch_add -> relaxed poll.
// out/xpf stay normal stores (same-WG / host-after-exit consumers) and are
// issued AFTER the drain point, so they never gate the barrier signal.
// xp for step t+1 is prefetched after the drain too: its HBM latency
// overlaps the tid0 poll window instead of sitting before the signal.
// ---------------------------------------------------------------------------
__global__ __launch_bounds__(1024) void rnn_scan(
    const unsigned short* __restrict__ WhTh, // [1024 cols][1024 k] bf16 hi
    const unsigned short* __restrict__ WhTl, // lo
    float* __restrict__ xpf,                 // [512*64*1024] f32 (= out[1])
    unsigned short* __restrict__ h0,
    unsigned short* __restrict__ h1,
    float* __restrict__ out,                 // out[0] region
    int* __restrict__ bar)
{
  __shared__ unsigned short hS[32768];  // 64 rows x 512 k, 16B-chunk XOR swizzle
  const int tid = threadIdx.x;
  const int w = tid >> 6, l = tid & 63;
  const int mt = w & 3, nt = w >> 2;
  const int col0 = blockIdx.x * 64;
  const int q = l >> 4, m = l & 15;
  const int colg = col0 + nt * 16 + m;
  const int arow = mt * 16 + m;

  // prefetch xp for t=0 (own slice; written by gemm_xp, inter-kernel coherent)
  float xp[4];
#pragma unroll
  for (int r = 0; r < 4; r++) {
    int brow = mt * 16 + q * 4 + r;
    xp[r] = xpf[(size_t)brow * CH + colg];
  }

  for (int t = 0; t < T_STEPS; t++) {
    const unsigned short* hsrc = (t & 1) ? h1 : h0;
    unsigned short* hdst = (t & 1) ? h0 : h1;
    f32x4 acc = {0.f, 0.f, 0.f, 0.f};
#pragma unroll
    for (int c = 0; c < 2; c++) {
      // stage 64 rows x 512 k of h into LDS via 8B agent-scope bypass loads
#pragma unroll
      for (int i = 0; i < 8; i++) {
        int cid = tid + i * 1024;
        int r = cid >> 7;          // row 0..63
        int e = cid & 127;         // 8B unit within 1024B (512-short) half-row
        unsigned long long v = __hip_atomic_load(
            (const unsigned long long*)(hsrc + (size_t)r * 1024 + c * 512 + e * 4),
            __ATOMIC_RELAXED, __HIP_MEMORY_SCOPE_AGENT);
        *(unsigned long long*)((char*)hS + r * 1024 + (((e >> 1) ^ (r & 7)) * 16) + (e & 1) * 8) = v;
      }
      __syncthreads();
#pragma unroll 4
      for (int kk = 0; kk < 16; kk++) {
        int cl = kk * 4 + q;
        bf16x8 af = *(const bf16x8*)((const char*)hS + arow * 1024 + ((cl ^ (arow & 7)) * 16));
        size_t boff = (size_t)colg * CH + c * 512 + kk * 32 + q * 8;
        bf16x8 bh = *(const bf16x8*)(WhTh + boff);
        bf16x8 bl = *(const bf16x8*)(WhTl + boff);
        acc = __builtin_amdgcn_mfma_f32_16x16x32_bf16(af, bh, acc, 0, 0, 0);
        acc = __builtin_amdgcn_mfma_f32_16x16x32_bf16(af, bl, acc, 0, 0, 0);
      }
      __syncthreads();
    }
    size_t tbase = (size_t)t * (BATCH * CH);
    // 1) compute h and issue ONLY the agent-scope h-stores
    float hv4[4];
#pragma unroll
    for (int r = 0; r < 4; r++) {
      int brow = mt * 16 + q * 4 + r;
      float pre = acc[r] + xp[r];
      float hv = tanhf(pre);
      hv4[r] = hv;
      __hip_atomic_store(&hdst[brow * CH + colg], f2bf(hv),
                         __ATOMIC_RELAXED, __HIP_MEMORY_SCOPE_AGENT);
    }
    // 2) drain h-stores to the coherence point; all waves reach this point
    asm volatile("s_waitcnt vmcnt(0)" ::: "memory");
    __syncthreads();
    // 3) fire-and-forget: out/xpf stores and next-step xp prefetch.
    //    Their latency overlaps the barrier poll below.
#pragma unroll
    for (int r = 0; r < 4; r++) {
      int brow = mt * 16 + q * 4 + r;
      size_t off = tbase + (size_t)brow * CH + colg;
      out[off] = hv4[r];
      xpf[off] = hv4[r];               // out[1] := h (same-WG consumer only)
    }
    if (t + 1 < T_STEPS) {
#pragma unroll
      for (int r = 0; r < 4; r++) {
        int brow = mt * 16 + q * 4 + r;
        xp[r] = xpf[tbase + (size_t)(BATCH * CH) + (size_t)brow * CH + colg];
      }
    }
    // 4) signal + poll (relaxed agent atomics; no cache-maintenance ops)
    if (tid == 0) {
      __hip_atomic_fetch_add(bar, 1, __ATOMIC_RELAXED, __HIP_MEMORY_SCOPE_AGENT);
      int target = 16 * (t + 1);
      while (__hip_atomic_load(bar, __ATOMIC_RELAXED, __HIP_MEMORY_SCOPE_AGENT) < target) {
        __builtin_amdgcn_s_sleep(1);
      }
    }
    __syncthreads();
  }
}

// ---------------------------------------------------------------------------
extern "C" void kernel_launch(void* const* d_in, const int* in_sizes, int n_in,
                              void* d_out, int out_size, void* d_ws, size_t ws_size,
                              hipStream_t stream)
{
  const float* inputs = (const float*)d_in[0];  // [512,64,512]
  const float* state  = (const float*)d_in[1];  // [1,64,1024]
  const float* Wx     = (const float*)d_in[2];  // [512,1024]
  const float* Wh     = (const float*)d_in[3];  // [1024,1024]
  const float* bias   = (const float*)d_in[4];  // [1024]
  float* out = (float*)d_out;
  float* xpf = out + (size_t)T_STEPS * BATCH * CH;  // out[1] region doubles as xp scratch

  char* ws = (char*)d_ws;
  size_t off = 0;
  unsigned short* WxTh = (unsigned short*)(ws + off); off += (size_t)CH * CIN * 2;  // 1 MB
  unsigned short* WxTl = (unsigned short*)(ws + off); off += (size_t)CH * CIN * 2;  // 1 MB
  unsigned short* WhTh = (unsigned short*)(ws + off); off += (size_t)CH * CH * 2;   // 2 MB
  unsigned short* WhTl = (unsigned short*)(ws + off); off += (size_t)CH * CH * 2;   // 2 MB
  unsigned short* h0   = (unsigned short*)(ws + off); off += (size_t)BATCH * CH * 2;
  unsigned short* h1   = (unsigned short*)(ws + off); off += (size_t)BATCH * CH * 2;
  int* bar             = (int*)(ws + off);            off += 256;

  hipMemsetAsync(bar, 0, 256, stream);
  hipLaunchKernelGGL(transpose_cvt_split, dim3(CH / 32, CIN / 32), dim3(256), 0, stream,
                     Wx, WxTh, WxTl, CIN, CH);
  hipLaunchKernelGGL(transpose_cvt_split, dim3(CH / 32, CH / 32), dim3(256), 0, stream,
                     Wh, WhTh, WhTl, CH, CH);
  hipLaunchKernelGGL(cvt_f32_bf16, dim3((BATCH * CH / 4) / 256), dim3(256), 0, stream,
                     state, h0, BATCH * CH);
  hipLaunchKernelGGL(gemm_xp, dim3(CH / BN, (T_STEPS * BATCH) / BM), dim3(256), 0, stream,
                     inputs, WxTh, WxTl, bias, xpf);
  hipLaunchKernelGGL(rnn_scan, dim3(16), dim3(1024), 0, stream,
                     WhTh, WhTl, xpf, h0, h1, out, bar);
}

// Round 3
// 16572.879 us; speedup vs baseline: 1.4040x; 1.1003x over previous
//
#include <hip/hip_runtime.h>

#define T_STEPS 512
#define BATCH   64
#define CIN     512
#define CH      1024

typedef __attribute__((ext_vector_type(8))) short bf16x8;
typedef __attribute__((ext_vector_type(4))) float f32x4;
typedef unsigned long long ull;

__device__ __forceinline__ unsigned short f2bf(float f) {
  unsigned int x = __float_as_uint(f);
  x += 0x7fffu + ((x >> 16) & 1u);   // RNE
  return (unsigned short)(x >> 16);
}
__device__ __forceinline__ float bf2f(unsigned short u) {
  return __uint_as_float(((unsigned int)u) << 16);
}

// ---------------------------------------------------------------------------
// fp32 [R][C] -> bf16 hi/lo transpose+split.
// ilv=0: separate arrays oh/ol, layout [C][R]   (used for Wx)
// ilv=1: single array oh, layout [C][R/8][hi8|lo8] 16-short units (used for Wh)
// ---------------------------------------------------------------------------
__global__ __launch_bounds__(256) void transpose_cvt_split(
    const float* __restrict__ in, unsigned short* __restrict__ oh,
    unsigned short* __restrict__ ol, int R, int Cc, int ilv)
{
  __shared__ float tile[32][33];
  const int tx = threadIdx.x & 31, ty = threadIdx.x >> 5;
  const int bx = blockIdx.x * 32;  // C offset
  const int by = blockIdx.y * 32;  // R offset
#pragma unroll
  for (int i = 0; i < 32; i += 8)
    tile[ty + i][tx] = in[(size_t)(by + ty + i) * Cc + bx + tx];
  __syncthreads();
#pragma unroll
  for (int i = 0; i < 32; i += 8) {
    float w = tile[tx][ty + i];
    unsigned short hi = f2bf(w);
    unsigned short lo = f2bf(w - bf2f(hi));
    size_t col = (size_t)(bx + ty + i);
    size_t k = (size_t)(by + tx);
    if (ilv) {
      size_t base = (col * (size_t)(R >> 3) + (k >> 3)) * 16 + (k & 7);
      oh[base] = hi;
      oh[base + 8] = lo;
    } else {
      size_t o = col * R + k;
      oh[o] = hi;
      ol[o] = lo;
    }
  }
}

// ---------------------------------------------------------------------------
// fp32 -> bf16 elementwise (h0 = state).
// ---------------------------------------------------------------------------
__global__ void cvt_f32_bf16(const float* __restrict__ in,
                             unsigned short* __restrict__ outp, int n)
{
  int i = (blockIdx.x * blockDim.x + threadIdx.x) * 4;
  if (i < n) {
    float4 v = *(const float4*)(in + i);
    ushort4 o;
    o.x = f2bf(v.x); o.y = f2bf(v.y); o.z = f2bf(v.z); o.w = f2bf(v.w);
    *(ushort4*)(outp + i) = o;
  }
}

// ---------------------------------------------------------------------------
// xp = inputs @ Wx + b, COMPENSATED bf16 GEMM -> fp32 output. (unchanged)
// ---------------------------------------------------------------------------
#define BM 128
#define BN 128
#define BK 32

__global__ __launch_bounds__(256) void gemm_xp(
    const float* __restrict__ A,
    const unsigned short* __restrict__ BTh,
    const unsigned short* __restrict__ BTl,
    const float* __restrict__ bias,
    float* __restrict__ C)                  // [32768][1024] f32 (out[1] region)
{
  __shared__ unsigned short Ah[BM][BK + 8];
  __shared__ unsigned short Al[BM][BK + 8];
  __shared__ unsigned short Bh[BN][BK + 8];
  __shared__ unsigned short Bl[BN][BK + 8];
  const int tid = threadIdx.x;
  const int w = tid >> 6, l = tid & 63;
  const int wm = (w >> 1) * 64, wn = (w & 1) * 64;
  const int q = l >> 4, m = l & 15;
  const int row0 = blockIdx.y * BM;
  const int col0 = blockIdx.x * BN;
  f32x4 acc[4][4];
#pragma unroll
  for (int i = 0; i < 4; i++)
#pragma unroll
    for (int j = 0; j < 4; j++) acc[i][j] = (f32x4){0.f, 0.f, 0.f, 0.f};

  for (int kt = 0; kt < CIN; kt += BK) {
#pragma unroll
    for (int i = 0; i < 4; i++) {
      int cid = tid + i * 256;
      int r = cid >> 3, c4 = cid & 7;
      float4 v = *(const float4*)(A + (size_t)(row0 + r) * CIN + kt + c4 * 4);
      ushort4 hi, lo;
      hi.x = f2bf(v.x); lo.x = f2bf(v.x - bf2f(hi.x));
      hi.y = f2bf(v.y); lo.y = f2bf(v.y - bf2f(hi.y));
      hi.z = f2bf(v.z); lo.z = f2bf(v.z - bf2f(hi.z));
      hi.w = f2bf(v.w); lo.w = f2bf(v.w - bf2f(hi.w));
      *(ushort4*)(&Ah[r][c4 * 4]) = hi;
      *(ushort4*)(&Al[r][c4 * 4]) = lo;
    }
#pragma unroll
    for (int i = 0; i < 4; i++) {
      int cid = tid + i * 256;
      const unsigned short* src = (cid < 512) ? BTh : BTl;
      unsigned short (*dst)[BK + 8] = (cid < 512) ? Bh : Bl;
      int rem = cid & 511;
      int r = rem >> 2, c8 = rem & 3;
      uint4 u = *(const uint4*)(src + (size_t)(col0 + r) * CIN + kt + c8 * 8);
      *(uint4*)(&dst[r][c8 * 8]) = u;
    }
    __syncthreads();
    bf16x8 ah[4], al[4], bh[4], bl[4];
#pragma unroll
    for (int i = 0; i < 4; i++) {
      ah[i] = *(const bf16x8*)(&Ah[wm + i * 16 + m][q * 8]);
      al[i] = *(const bf16x8*)(&Al[wm + i * 16 + m][q * 8]);
    }
#pragma unroll
    for (int j = 0; j < 4; j++) {
      bh[j] = *(const bf16x8*)(&Bh[wn + j * 16 + m][q * 8]);
      bl[j] = *(const bf16x8*)(&Bl[wn + j * 16 + m][q * 8]);
    }
#pragma unroll
    for (int i = 0; i < 4; i++)
#pragma unroll
      for (int j = 0; j < 4; j++) {
        acc[i][j] = __builtin_amdgcn_mfma_f32_16x16x32_bf16(ah[i], bh[j], acc[i][j], 0, 0, 0);
        acc[i][j] = __builtin_amdgcn_mfma_f32_16x16x32_bf16(ah[i], bl[j], acc[i][j], 0, 0, 0);
        acc[i][j] = __builtin_amdgcn_mfma_f32_16x16x32_bf16(al[i], bh[j], acc[i][j], 0, 0, 0);
      }
    __syncthreads();
  }
#pragma unroll
  for (int i = 0; i < 4; i++) {
#pragma unroll
    for (int j = 0; j < 4; j++) {
      int col = col0 + wn + j * 16 + m;
      float bv = bias[col];
#pragma unroll
      for (int r = 0; r < 4; r++) {
        int row = row0 + wm + i * 16 + q * 4 + r;
        C[(size_t)row * CH + col] = acc[i][j][r] + bv;
      }
    }
  }
}

// ---------------------------------------------------------------------------
// Persistent scan: h_{t+1} = tanh(xp_t + h_t @ Wh), 512 steps.
// 16 WGs x 1024 threads; WG owns 64 cols.
//
// This revision compresses the per-step latency chain:
//  - SINGLE-PHASE staging: all 16x8B bypass loads issued up-front into regs,
//    hS = full 128 KB [64 rows][128 16B-units], one sync instead of four.
//  - Wh hi/lo INTERLEAVED [col][k/8][hi8|lo8]: one 32B-contiguous stream/lane.
//  - Coalesced h-store: LDS transpose (stride-76 pad) -> one 8B agent-scope
//    store per thread (128B contiguous per row) before the barrier signal.
//  - Hot-spin barrier (no s_sleep), signal before shadow work.
//  - out/xpf stores + next-step xp prefetch in the poll shadow.
// ---------------------------------------------------------------------------
__global__ __launch_bounds__(1024) void rnn_scan(
    const unsigned short* __restrict__ WhTi, // [1024 cols][128][hi8|lo8] bf16
    float* __restrict__ xpf,                 // [512*64*1024] f32 (= out[1])
    unsigned short* __restrict__ h0,
    unsigned short* __restrict__ h1,
    float* __restrict__ out,                 // out[0] region
    int* __restrict__ bar)
{
  __shared__ unsigned short hS[65536];              // 128 KB staged h
  __shared__ __align__(8) unsigned short hX[64 * 76]; // 9.5 KB transpose buf
  const int tid = threadIdx.x;
  const int w = tid >> 6, l = tid & 63;
  const int mt = w & 3, nt = w >> 2;
  const int col0 = blockIdx.x * 64;
  const int q = l >> 4, m = l & 15;
  const int colg = col0 + nt * 16 + m;
  const int arow = mt * 16 + m;

  // xp prefetch for t=0 (own slice; gemm_xp output, inter-kernel coherent)
  float xp[4];
#pragma unroll
  for (int r = 0; r < 4; r++) {
    int brow = mt * 16 + q * 4 + r;
    xp[r] = xpf[(size_t)brow * CH + colg];
  }

  for (int t = 0; t < T_STEPS; t++) {
    const unsigned short* hsrc = (t & 1) ? h1 : h0;
    unsigned short* hdst = (t & 1) ? h0 : h1;

    // ---- stage all of h: 16 x 8B bypass loads issued up-front ----
    ull hv[16];
#pragma unroll
    for (int i = 0; i < 16; i++) {
      int cid = i * 1024 + tid;            // 16384 8B-units: [64 rows][256]
      int r = cid >> 8, e = cid & 255;
      hv[i] = __hip_atomic_load((const ull*)(hsrc + (size_t)r * 1024 + e * 4),
                                __ATOMIC_RELAXED, __HIP_MEMORY_SCOPE_AGENT);
    }
#pragma unroll
    for (int i = 0; i < 16; i++) {
      int cid = i * 1024 + tid;
      int r = cid >> 8, e = cid & 255;
      int u16 = e >> 1, sub = e & 1;       // 16B unit, XOR swizzle in 8-groups
      *(ull*)((char*)hS + r * 2048 + ((u16 ^ (r & 7)) * 16) + sub * 8) = hv[i];
    }
    __syncthreads();                       // S1

    // ---- MFMA: 32 k-groups, weights hi/lo interleaved 32B per lane ----
    f32x4 acc = {0.f, 0.f, 0.f, 0.f};
#pragma unroll 4
    for (int kk = 0; kk < 32; kk++) {
      int cl = kk * 4 + q;                 // 16B-unit index 0..127 (= k/8)
      bf16x8 af = *(const bf16x8*)((const char*)hS + arow * 2048 +
                                   ((cl ^ (arow & 7)) * 16));
      const unsigned short* wp = WhTi + ((size_t)colg * 128 + cl) * 16;
      bf16x8 bh = *(const bf16x8*)(wp);
      bf16x8 bl = *(const bf16x8*)(wp + 8);
      acc = __builtin_amdgcn_mfma_f32_16x16x32_bf16(af, bh, acc, 0, 0, 0);
      acc = __builtin_amdgcn_mfma_f32_16x16x32_bf16(af, bl, acc, 0, 0, 0);
    }
    __syncthreads();                       // S2 (hS reads done)

    // ---- epilogue: tanh, transpose in LDS for coalesced h-store ----
    size_t tbase = (size_t)t * (BATCH * CH);
    float hv4[4];
#pragma unroll
    for (int r = 0; r < 4; r++) {
      int brow = mt * 16 + q * 4 + r;
      float pre = acc[r] + xp[r];
      // fast tanh: 1 - 2/(e^{2x}+1); saturates correctly at +/-inf
      float e2 = __expf(2.f * pre);
      float hvf = 1.f - 2.f / (e2 + 1.f);
      hv4[r] = hvf;
      hX[brow * 76 + nt * 16 + m] = f2bf(hvf);
    }
    __syncthreads();                       // S3
    {
      int rrow = tid >> 4, ch = tid & 15;  // 64 rows x 16 8B-chunks
      ull v8 = *(const ull*)(&hX[rrow * 76 + ch * 4]);
      __hip_atomic_store((ull*)(hdst + (size_t)rrow * 1024 + col0 + ch * 4), v8,
                         __ATOMIC_RELAXED, __HIP_MEMORY_SCOPE_AGENT);
    }
    asm volatile("s_waitcnt vmcnt(0)" ::: "memory");  // drain h-stores
    __syncthreads();                       // S4 (whole WG's h at coherence pt)

    if (tid == 0)                          // signal ASAP
      __hip_atomic_fetch_add(bar, 1, __ATOMIC_RELAXED, __HIP_MEMORY_SCOPE_AGENT);

    // shadow work: out/xpf stores + next-step xp prefetch overlap the poll
#pragma unroll
    for (int r = 0; r < 4; r++) {
      int brow = mt * 16 + q * 4 + r;
      size_t off = tbase + (size_t)brow * CH + colg;
      out[off] = hv4[r];
      xpf[off] = hv4[r];
    }
    if (t + 1 < T_STEPS) {
#pragma unroll
      for (int r = 0; r < 4; r++) {
        int brow = mt * 16 + q * 4 + r;
        xp[r] = xpf[tbase + (size_t)(BATCH * CH) + (size_t)brow * CH + colg];
      }
    }

    if (tid == 0) {                        // hot spin (no s_sleep)
      int target = 16 * (t + 1);
      while (__hip_atomic_load(bar, __ATOMIC_RELAXED,
                               __HIP_MEMORY_SCOPE_AGENT) < target) {}
    }
    __syncthreads();                       // S5 (barrier release)
  }
}

// ---------------------------------------------------------------------------
extern "C" void kernel_launch(void* const* d_in, const int* in_sizes, int n_in,
                              void* d_out, int out_size, void* d_ws, size_t ws_size,
                              hipStream_t stream)
{
  const float* inputs = (const float*)d_in[0];  // [512,64,512]
  const float* state  = (const float*)d_in[1];  // [1,64,1024]
  const float* Wx     = (const float*)d_in[2];  // [512,1024]
  const float* Wh     = (const float*)d_in[3];  // [1024,1024]
  const float* bias   = (const float*)d_in[4];  // [1024]
  float* out = (float*)d_out;
  float* xpf = out + (size_t)T_STEPS * BATCH * CH;  // out[1] region = xp scratch

  char* ws = (char*)d_ws;
  size_t off = 0;
  unsigned short* WxTh = (unsigned short*)(ws + off); off += (size_t)CH * CIN * 2;  // 1 MB
  unsigned short* WxTl = (unsigned short*)(ws + off); off += (size_t)CH * CIN * 2;  // 1 MB
  unsigned short* WhTi = (unsigned short*)(ws + off); off += (size_t)CH * CH * 4;   // 4 MB interleaved
  unsigned short* h0   = (unsigned short*)(ws + off); off += (size_t)BATCH * CH * 2;
  unsigned short* h1   = (unsigned short*)(ws + off); off += (size_t)BATCH * CH * 2;
  int* bar             = (int*)(ws + off);            off += 256;

  hipMemsetAsync(bar, 0, 256, stream);
  hipLaunchKernelGGL(transpose_cvt_split, dim3(CH / 32, CIN / 32), dim3(256), 0, stream,
                     Wx, WxTh, WxTl, CIN, CH, 0);
  hipLaunchKernelGGL(transpose_cvt_split, dim3(CH / 32, CH / 32), dim3(256), 0, stream,
                     Wh, WhTi, (unsigned short*)nullptr, CH, CH, 1);
  hipLaunchKernelGGL(cvt_f32_bf16, dim3((BATCH * CH / 4) / 256), dim3(256), 0, stream,
                     state, h0, BATCH * CH);
  hipLaunchKernelGGL(gemm_xp, dim3(CH / BN, (T_STEPS * BATCH) / BM), dim3(256), 0, stream,
                     inputs, WxTh, WxTl, bias, xpf);
  hipLaunchKernelGGL(rnn_scan, dim3(16), dim3(1024), 0, stream,
                     WhTi, xpf, h0, h1, out, bar);
}